// Round 2
// baseline (790.168 us; speedup 1.0000x reference)
//
#include <hip/hip_runtime.h>
#include <stdint.h>

#define NTOK 8192
#define HDIM 2048
#define NE   16
#define CAP  640
// dispatch/combine each: 8192*16*640 = 83,886,080 floats
#define DCOFF 83886080ULL
#define USAGEOFF 167772160ULL
#define LLOFF 167772176ULL
#define ZLOFF 167772177ULL

// workspace byte offsets
#define WS_KEY   0        // unsigned long long[8192]
#define WS_GATE  65536    // float[8192]
#define WS_EIDX  98304    // int[8192]
#define WS_RANK  131072   // int[8192]
#define WS_COL   163840   // float[16]
#define WS_CNT   163904   // int[16]
#define WS_Z     163968   // float[1]

__global__ __launch_bounds__(256)
void zero_ws_kernel(uint32_t* __restrict__ p, int n) {
    int i = blockIdx.x * 256 + threadIdx.x;
    if (i < n) p[i] = 0u;
}

// Fused kernel: blocks [0,512) do routing (16 tokens each, 1 wave = 4 tokens,
// lanes along H); blocks [512, 512+2048) zero the 671MB dispatch+combine
// region. Router blocks come first so their HBM reads overlap the write
// stream (no data dependence between the two phases; mixed R+W hits the
// same ~6.3 TB/s ceiling as pure streams).
__global__ __launch_bounds__(256)
void router_zero_kernel(const float* __restrict__ hs, const float* __restrict__ rw,
                        const float* __restrict__ noise,
                        unsigned long long* __restrict__ key,
                        float* __restrict__ gateA, int* __restrict__ eidxA,
                        float* __restrict__ colsum, int* __restrict__ counts,
                        float* __restrict__ zsum, float4* __restrict__ outv)
{
    const int tid = threadIdx.x;

    if (blockIdx.x >= 512) {
        // ---- zero path: 2048 blocks * 256 thr * 80 float4 = 167,772,160 floats
        size_t idx = (size_t)(blockIdx.x - 512) * 256 + tid;
        const size_t stride = (size_t)2048 * 256;
        const float4 z = make_float4(0.f, 0.f, 0.f, 0.f);
        #pragma unroll 4
        for (int k = 0; k < 80; ++k) {
            outv[idx] = z;
            idx += stride;
        }
        return;
    }

    // ---- router path
    __shared__ float lcol[NE];
    __shared__ int   lcnt[NE];
    __shared__ float lz;
    if (tid < NE) { lcol[tid] = 0.f; lcnt[tid] = 0; }
    if (tid == 0) lz = 0.f;
    __syncthreads();

    const int wave = tid >> 6;
    const int lane = tid & 63;
    const int tok0 = blockIdx.x * 16 + wave * 4;

    float acc[4][NE];
    #pragma unroll
    for (int t = 0; t < 4; ++t)
        #pragma unroll
        for (int e = 0; e < NE; ++e) acc[t][e] = 0.f;

    for (int c = 0; c < 8; ++c) {
        const int h = c * 256 + lane * 4;
        float4 x[4];
        #pragma unroll
        for (int t = 0; t < 4; ++t) {
            const float4 hv = *reinterpret_cast<const float4*>(hs + (size_t)(tok0 + t) * HDIM + h);
            const float4 nv = *reinterpret_cast<const float4*>(noise + (size_t)(tok0 + t) * HDIM + h);
            x[t].x = hv.x + (nv.x * 2.f - 1.f) * 0.1f;
            x[t].y = hv.y + (nv.y * 2.f - 1.f) * 0.1f;
            x[t].z = hv.z + (nv.z * 2.f - 1.f) * 0.1f;
            x[t].w = hv.w + (nv.w * 2.f - 1.f) * 0.1f;
        }
        #pragma unroll
        for (int e = 0; e < NE; ++e) {
            const float4 wv = *reinterpret_cast<const float4*>(rw + e * HDIM + h);
            #pragma unroll
            for (int t = 0; t < 4; ++t) {
                acc[t][e] = fmaf(x[t].x, wv.x, acc[t][e]);
                acc[t][e] = fmaf(x[t].y, wv.y, acc[t][e]);
                acc[t][e] = fmaf(x[t].z, wv.z, acc[t][e]);
                acc[t][e] = fmaf(x[t].w, wv.w, acc[t][e]);
            }
        }
    }

    // all-reduce across the 64 lanes (butterfly); afterwards every lane holds full sums
    #pragma unroll
    for (int m = 1; m < 64; m <<= 1)
        #pragma unroll
        for (int t = 0; t < 4; ++t)
            #pragma unroll
            for (int e = 0; e < NE; ++e)
                acc[t][e] += __shfl_xor(acc[t][e], m, 64);

    if (lane < 4) {
        // static-index selection of this lane's token row (avoid scratch spill)
        float l[NE];
        #pragma unroll
        for (int e = 0; e < NE; ++e)
            l[e] = (lane == 0) ? acc[0][e] : (lane == 1) ? acc[1][e]
                 : (lane == 2) ? acc[2][e] : acc[3][e];

        const int tok = tok0 + lane;
        float mx = l[0]; int ei = 0;
        #pragma unroll
        for (int e = 1; e < NE; ++e) if (l[e] > mx) { mx = l[e]; ei = e; }  // first-max like argmax

        float s = 0.f, z = 0.f;
        float p[NE];
        #pragma unroll
        for (int e = 0; e < NE; ++e) {
            z = fmaf(l[e], l[e], z);
            p[e] = expf(l[e] - mx);
            s += p[e];
        }
        const float g = 1.f / s;  // max prob = exp(0)/s
        gateA[tok] = g;
        eidxA[tok] = ei;
        // sort key: expert asc (high bits), then gate desc, then token asc.
        // gate>0 so its float bits are order-monotonic as uint; 8191-tok makes
        // "greater key" == "earlier token" on gate ties (stable-sort semantics).
        key[tok] = ((unsigned long long)ei << 45)
                 | ((unsigned long long)__float_as_uint(g) << 13)
                 | (unsigned long long)(8191 - tok);

        #pragma unroll
        for (int e = 0; e < NE; ++e) atomicAdd(&lcol[e], p[e] * g);
        atomicAdd(&lcnt[ei], 1);
        atomicAdd(&lz, z);
    }
    __syncthreads();
    if (tid < NE) {
        atomicAdd(&colsum[tid], lcol[tid]);
        atomicAdd(&counts[tid], lcnt[tid]);
    }
    if (tid == 0) atomicAdd(zsum, lz);
}

// rank[i] = #{j : expert(j)==expert(i), key_j > key_i}  (== lexsort position in expert)
__global__ __launch_bounds__(256)
void rank_kernel(const unsigned long long* __restrict__ key, int* __restrict__ rnk)
{
    __shared__ unsigned long long kb[1024];
    const int tid = threadIdx.x;
    const int i  = (blockIdx.x >> 3) * 256 + tid;
    const int j0 = (blockIdx.x & 7) * 1024;
    const unsigned long long ki = key[i];
    const unsigned long long me = ki >> 45;
    #pragma unroll
    for (int k = 0; k < 4; ++k) kb[tid + k * 256] = key[j0 + tid + k * 256];
    __syncthreads();
    int cnt = 0;
    #pragma unroll 8
    for (int j = 0; j < 1024; ++j) {
        const unsigned long long kj = kb[j];   // uniform address -> LDS broadcast
        cnt += (int)(((kj >> 45) == me) & (kj > ki));
    }
    if (cnt) atomicAdd(&rnk[i], cnt);
}

__global__ __launch_bounds__(256)
void scatter_kernel(const int* __restrict__ rnk, const int* __restrict__ eidxA,
                    const float* __restrict__ gateA,
                    const float* __restrict__ colsum, const int* __restrict__ counts,
                    const float* __restrict__ zsum, float* __restrict__ out)
{
    const int i = blockIdx.x * 256 + threadIdx.x;
    if (i < NTOK) {
        const int r = rnk[i];
        if (r < CAP) {
            const size_t off = (size_t)i * (NE * CAP) + (size_t)eidxA[i] * CAP + r;
            out[off] = 1.0f;
            out[DCOFF + off] = gateA[i];
        }
    } else if (i < NTOK + NE) {
        const int e = i - NTOK;
        const int c = counts[e];
        out[USAGEOFF + e] = (float)(c < CAP ? c : CAP);
    } else if (i == NTOK + NE) {
        float ll = 0.f;
        #pragma unroll
        for (int e = 0; e < NE; ++e) ll += colsum[e] * (float)counts[e];
        out[LLOFF] = 16.f * ll / (8192.f * 8192.f);  // E * sum(mean_probs * frac)
    } else if (i == NTOK + NE + 1) {
        out[ZLOFF] = zsum[0] / 131072.f;  // mean over N*E
    }
}

extern "C" void kernel_launch(void* const* d_in, const int* in_sizes, int n_in,
                              void* d_out, int out_size, void* d_ws, size_t ws_size,
                              hipStream_t stream)
{
    const float* hs    = (const float*)d_in[0];
    const float* rw    = (const float*)d_in[1];
    const float* noise = (const float*)d_in[2];
    float* out = (float*)d_out;
    char* ws = (char*)d_ws;

    unsigned long long* key = (unsigned long long*)(ws + WS_KEY);
    float* gateA  = (float*)(ws + WS_GATE);
    int*   eidxA  = (int*)(ws + WS_EIDX);
    int*   rnk    = (int*)(ws + WS_RANK);
    float* colsum = (float*)(ws + WS_COL);
    int*   counts = (int*)(ws + WS_CNT);
    float* zsum   = (float*)(ws + WS_Z);

    // zero rank + colsum + counts + zsum (contiguous: 8192+16+16+1 = 8225 dwords)
    hipLaunchKernelGGL(zero_ws_kernel, dim3(33), dim3(256), 0, stream,
                       (uint32_t*)(ws + WS_RANK), 8225);
    // fused: router (blocks 0..511) + 671MB output zero-fill (blocks 512..2559)
    hipLaunchKernelGGL(router_zero_kernel, dim3(2560), dim3(256), 0, stream,
                       hs, rw, noise, key, gateA, eidxA, colsum, counts, zsum,
                       (float4*)d_out);
    hipLaunchKernelGGL(rank_kernel, dim3(256), dim3(256), 0, stream, key, rnk);
    hipLaunchKernelGGL(scatter_kernel, dim3(33), dim3(256), 0, stream,
                       rnk, eidxA, gateA, colsum, counts, zsum, out);
}